// Round 1
// baseline (47.172 us; speedup 1.0000x reference)
//
#include <hip/hip_runtime.h>
#include <math.h>

#define AMP_C 100.0f
#define NSD_SCALE_C 500.0f
#define NSD_SLOPE_C 10.0f

// ---------------------------------------------------------------------------
// prep_kernel: 1 thread. Collapses t, M, K, C into 22 coefficients in d_ws:
//   p[0..8]  = A  = -M^-1 K        (row-major)
//   p[9..17] = Bc = -M^-1 C        (row-major)
//   p[18..20]= M^-1 column 0       (multiplies f_nsd)
//   p[21]    = -AMP * sin(2*pi*t)  (a_base, same for all 3 components)
// ---------------------------------------------------------------------------
__global__ void prep_kernel(const float* __restrict__ t,
                            const float* __restrict__ M,
                            const float* __restrict__ K,
                            const float* __restrict__ C,
                            float* __restrict__ p) {
    if (threadIdx.x != 0 || blockIdx.x != 0) return;
    float m00 = M[0], m01 = M[1], m02 = M[2];
    float m10 = M[3], m11 = M[4], m12 = M[5];
    float m20 = M[6], m21 = M[7], m22 = M[8];
    float det = m00 * (m11 * m22 - m12 * m21)
              - m01 * (m10 * m22 - m12 * m20)
              + m02 * (m10 * m21 - m11 * m20);
    float id = 1.0f / det;
    float inv[9];
    inv[0] =  (m11 * m22 - m12 * m21) * id;
    inv[1] = -(m01 * m22 - m02 * m21) * id;
    inv[2] =  (m01 * m12 - m02 * m11) * id;
    inv[3] = -(m10 * m22 - m12 * m20) * id;
    inv[4] =  (m00 * m22 - m02 * m20) * id;
    inv[5] = -(m00 * m12 - m02 * m10) * id;
    inv[6] =  (m10 * m21 - m11 * m20) * id;
    inv[7] = -(m00 * m21 - m01 * m20) * id;
    inv[8] =  (m00 * m11 - m01 * m10) * id;
    for (int r = 0; r < 3; ++r) {
        for (int c = 0; c < 3; ++c) {
            float sK = 0.0f, sC = 0.0f;
            for (int k = 0; k < 3; ++k) {
                sK += inv[3 * r + k] * K[3 * k + c];
                sC += inv[3 * r + k] * C[3 * k + c];
            }
            p[3 * r + c]     = -sK;
            p[9 + 3 * r + c] = -sC;
        }
    }
    p[18] = inv[0];
    p[19] = inv[3];
    p[20] = inv[6];
    p[21] = -AMP_C * sinf(6.28318530717958647692f * t[0]);
}

// ---------------------------------------------------------------------------
// fused_kernel: 2 rows per thread, 3x float4 load + 3x float4 store (all
// 16B-aligned since a row pair is 48B). Memory-bound streaming map.
// ---------------------------------------------------------------------------
__global__ __launch_bounds__(256) void fused_kernel(
        const float4* __restrict__ h4,
        float4* __restrict__ o4,
        const float* __restrict__ hs,   // scalar view for odd tail
        float* __restrict__ os,
        const float* __restrict__ p,
        int npairs, int nrows) {
    // broadcast coefficients (uniform address -> cached, cheap)
    const float A00 = p[0],  A01 = p[1],  A02 = p[2];
    const float A10 = p[3],  A11 = p[4],  A12 = p[5];
    const float A20 = p[6],  A21 = p[7],  A22 = p[8];
    const float B00 = p[9],  B01 = p[10], B02 = p[11];
    const float B10 = p[12], B11 = p[13], B12 = p[14];
    const float B20 = p[15], B21 = p[16], B22 = p[17];
    const float mi0 = p[18], mi1 = p[19], mi2 = p[20];
    const float base = p[21];

    const int i = blockIdx.x * blockDim.x + threadIdx.x;
    if (i < npairs) {
        const size_t b = (size_t)3 * (size_t)i;
        float4 ha = h4[b + 0];
        float4 hb = h4[b + 1];
        float4 hc = h4[b + 2];
        // row0: x=(ha.x,ha.y,ha.z) v=(ha.w,hb.x,hb.y)
        // row1: x=(hb.z,hb.w,hc.x) v=(hc.y,hc.z,hc.w)
        float x[2][3] = {{ha.x, ha.y, ha.z}, {hb.z, hb.w, hc.x}};
        float v[2][3] = {{ha.w, hb.x, hb.y}, {hc.y, hc.z, hc.w}};
        float a[2][3];
#pragma unroll
        for (int r = 0; r < 2; ++r) {
            float f = -NSD_SCALE_C * tanhf(NSD_SLOPE_C * x[r][0]);
            float cmn = base;
            a[r][0] = A00 * x[r][0] + A01 * x[r][1] + A02 * x[r][2]
                    + B00 * v[r][0] + B01 * v[r][1] + B02 * v[r][2] + cmn + f * mi0;
            a[r][1] = A10 * x[r][0] + A11 * x[r][1] + A12 * x[r][2]
                    + B10 * v[r][0] + B11 * v[r][1] + B12 * v[r][2] + cmn + f * mi1;
            a[r][2] = A20 * x[r][0] + A21 * x[r][1] + A22 * x[r][2]
                    + B20 * v[r][0] + B21 * v[r][1] + B22 * v[r][2] + cmn + f * mi2;
        }
        float4 oa = make_float4(v[0][0], v[0][1], v[0][2], a[0][0]);
        float4 ob = make_float4(a[0][1], a[0][2], v[1][0], v[1][1]);
        float4 oc = make_float4(v[1][2], a[1][0], a[1][1], a[1][2]);
        o4[b + 0] = oa;
        o4[b + 1] = ob;
        o4[b + 2] = oc;
    } else if (i == npairs && (nrows & 1)) {
        // odd tail: last row, scalar path
        const size_t r0 = (size_t)(nrows - 1) * 6;
        float x0 = hs[r0 + 0], x1 = hs[r0 + 1], x2 = hs[r0 + 2];
        float v0 = hs[r0 + 3], v1 = hs[r0 + 4], v2 = hs[r0 + 5];
        float f = -NSD_SCALE_C * tanhf(NSD_SLOPE_C * x0);
        float a0 = A00 * x0 + A01 * x1 + A02 * x2 + B00 * v0 + B01 * v1 + B02 * v2 + base + f * mi0;
        float a1 = A10 * x0 + A11 * x1 + A12 * x2 + B10 * v0 + B11 * v1 + B12 * v2 + base + f * mi1;
        float a2 = A20 * x0 + A21 * x1 + A22 * x2 + B20 * v0 + B21 * v1 + B22 * v2 + base + f * mi2;
        os[r0 + 0] = v0; os[r0 + 1] = v1; os[r0 + 2] = v2;
        os[r0 + 3] = a0; os[r0 + 4] = a1; os[r0 + 5] = a2;
    }
}

extern "C" void kernel_launch(void* const* d_in, const int* in_sizes, int n_in,
                              void* d_out, int out_size, void* d_ws, size_t ws_size,
                              hipStream_t stream) {
    const float* t = (const float*)d_in[0];
    const float* h = (const float*)d_in[1];
    const float* M = (const float*)d_in[2];
    const float* K = (const float*)d_in[3];
    const float* C = (const float*)d_in[4];
    float* out = (float*)d_out;
    float* p   = (float*)d_ws;

    const int nrows = in_sizes[1] / 6;
    const int npairs = nrows / 2;

    prep_kernel<<<1, 64, 0, stream>>>(t, M, K, C, p);

    const int total = npairs + (nrows & 1);
    const int block = 256;
    const int grid = (total + block - 1) / block;
    fused_kernel<<<grid, block, 0, stream>>>(
        (const float4*)h, (float4*)out, h, out, p, npairs, nrows);
}